// Round 6
// baseline (320.691 us; speedup 1.0000x reference)
//
#include <hip/hip_runtime.h>
#include <hip/hip_bf16.h>

typedef __attribute__((ext_vector_type(8))) short short8;
typedef __attribute__((ext_vector_type(4))) float floatx4;

#define SCALE 0.17677669529663687f  /* 1/sqrt(32) */

__device__ __forceinline__ unsigned short f2bf(float f) {
  unsigned int x = __float_as_uint(f);
  x += 0x7fffu + ((x >> 16) & 1u);   // RNE
  return (unsigned short)(x >> 16);
}
__device__ __forceinline__ float bf2f(unsigned short u) {
  return __uint_as_float(((unsigned int)u) << 16);
}

// load 8 consecutive floats, convert to bf16 MFMA frag
__device__ __forceinline__ short8 load_cvt8(const float* p) {
  floatx4 a = *(const floatx4*)p;
  floatx4 b = *(const floatx4*)(p + 4);
  short8 r;
  r[0] = (short)f2bf(a[0]); r[1] = (short)f2bf(a[1]);
  r[2] = (short)f2bf(a[2]); r[3] = (short)f2bf(a[3]);
  r[4] = (short)f2bf(b[0]); r[5] = (short)f2bf(b[1]);
  r[6] = (short)f2bf(b[2]); r[7] = (short)f2bf(b[3]);
  return r;
}

// ---------------- setup A: q_all[b,:] = tgt_b @ Wq_c  (row B = seed @ Wq_p) ----------------
__global__ __launch_bounds__(256) void k_qc_gemm(
    const float* __restrict__ node, const int* __restrict__ tgt_idx,
    const float* __restrict__ seed,
    const float* __restrict__ Wq_c, const float* __restrict__ Wq_p,
    float* __restrict__ q_all, int B)
{
  __shared__ float act_l[4 * 256];
  const int tid = threadIdx.x;
  const int bt = blockIdx.x, nt = blockIdx.y;
  const int BT = B >> 2;
  for (int i = tid; i < 4 * 256; i += 256) {
    int m = i >> 8, k = i & 255;
    int b = bt * 4 + m;
    float v = 0.f;
    if (b < B)       v = node[(size_t)tgt_idx[b] * 256 + k];
    else if (b == B) v = seed[k];
    act_l[i] = v;
  }
  __syncthreads();
  const float* W = (bt == BT) ? Wq_p : Wq_c;
  const int m = tid >> 6, lane = tid & 63, ks = lane >> 4, n = lane & 15;
  const int n0 = nt * 16;
  float acc = 0.f;
  const float* Wp = W + (size_t)(ks * 64) * 256 + n0 + n;
  const float* ap = &act_l[m * 256 + ks * 64];
  #pragma unroll 8
  for (int k = 0; k < 64; ++k) acc += ap[k] * Wp[(size_t)k * 256];
  acc += __shfl_xor(acc, 16, 64);
  acc += __shfl_xor(acc, 32, 64);
  const int b = bt * 4 + m;
  if (ks == 0 && b <= B) q_all[(size_t)b * 256 + n0 + n] = acc;
}

// ---------------- setup B: per-head fold u[b][h][d] = sum_j Wk[d, h*32+j] q[b, h*32+j] ----------------
// row b<B uses Wk_c -> u_c_all; row b==B uses Wk_p -> u_p_t. seg searches in dt==0 WGs.
__global__ __launch_bounds__(256) void k_fold(
    const float* __restrict__ Wk_c, const float* __restrict__ Wk_p,
    const float* __restrict__ q_all, const int* __restrict__ port_batch,
    unsigned short* __restrict__ u_c_all, unsigned short* __restrict__ u_p_t,
    int* __restrict__ seg, int T, int B)
{
  const int tid = threadIdx.x;
  const int bt = blockIdx.x, dt = blockIdx.y;
  const int BT = B >> 2;
  if (dt == 0) {
    int key = -1;
    if (bt < BT) { if (tid < 4) key = bt * 4 + tid; }
    else if (tid == 0) key = B;
    if (key >= 0) {
      int lo = 0, hi = T;
      while (lo < hi) { int mid = (lo + hi) >> 1; if (port_batch[mid] < key) lo = mid + 1; else hi = mid; }
      seg[key] = lo;
    }
  }
  const int m = tid >> 6, lane = tid & 63;
  const int b = bt * 4 + m;
  if (b > B) return;
  const float* Wk = (b == B) ? Wk_p : Wk_c;
  const float* q = q_all + (size_t)b * 256;
  #pragma unroll
  for (int t2 = 0; t2 < 2; ++t2) {
    const int idx = t2 * 64 + lane;
    const int h = idx >> 4;
    const int d = dt * 16 + (idx & 15);
    float acc = 0.f;
    const float* wr = Wk + (size_t)d * 256 + h * 32;
    const float* qr = q + h * 32;
    #pragma unroll 8
    for (int j = 0; j < 32; ++j) acc += wr[j] * qr[j];
    unsigned short v = f2bf(acc);
    if (b < B) u_c_all[(size_t)b * 2048 + h * 256 + d] = v;
    else       u_p_t[h * 256 + d] = v;
  }
}

// ---------------- attention: WG (s, b) handles tiles s, s+S, ... of segment b ----------------
__global__ __launch_bounds__(256, 2) void attn_kernel(
    const float* __restrict__ node,
    const int* __restrict__ port_index,
    const float* __restrict__ port_weight,
    const unsigned short* __restrict__ u_p_t,
    const unsigned short* __restrict__ u_c_all,
    const int* __restrict__ seg,
    float* __restrict__ slabs, int T, int S)
{
  __shared__ __align__(16) unsigned short tok_lds[64 * 264];
  __shared__ __align__(16) unsigned short E_t[16 * 72];
  __shared__ float l_lds[16];

  const int tid  = threadIdx.x;
  const int s    = blockIdx.x;
  const int b    = blockIdx.y;
  const int lane = tid & 63;
  const int w    = tid >> 6;
  const int q    = lane >> 4;
  const int n    = lane & 15;

  if (tid < 16) l_lds[tid] = 0.f;

  short8 ufrag[8];
  const unsigned short* ubase = (n < 8) ? (u_p_t + n * 256)
                                        : (u_c_all + (size_t)b * 2048 + (n - 8) * 256);
  #pragma unroll
  for (int s8 = 0; s8 < 8; ++s8)
    ufrag[s8] = *(const short8*)(ubase + q * 8 + s8 * 32);

  const int start  = seg[b];
  const int end    = seg[b + 1];
  const int ntiles = (end - start + 63) >> 6;

  floatx4 sacc[4];
  #pragma unroll
  for (int nt = 0; nt < 4; ++nt) sacc[nt] = (floatx4){0.f, 0.f, 0.f, 0.f};

  __syncthreads();   // l_lds init visible

  for (int it = s; it < ntiles; it += S) {
    const int tbase = start + it * 64;
    short8 cur[8];
    {
      int t = tbase + w * 16 + n; int tc = t < T ? t : T - 1;
      const float* rp = node + (size_t)port_index[tc] * 256 + q * 8;
      #pragma unroll
      for (int k = 0; k < 8; ++k) cur[k] = load_cvt8(rp + k * 32);
    }
    float pw[4];
    #pragma unroll
    for (int r = 0; r < 4; ++r) { int tr = tbase + w * 16 + q * 4 + r; pw[r] = port_weight[tr < T ? tr : T - 1]; }

    floatx4 lacc = (floatx4){0.f, 0.f, 0.f, 0.f};
    #pragma unroll
    for (int k = 0; k < 8; ++k)
      lacc = __builtin_amdgcn_mfma_f32_16x16x32_bf16(cur[k], ufrag[k], lacc, 0, 0, 0);
    float lsum = 0.f;
    #pragma unroll
    for (int r = 0; r < 4; ++r) {
      const int tr = tbase + w * 16 + q * 4 + r;
      float e = 0.f;
      if (tr < end) {
        float lg = lacc[r] * SCALE + logf(pw[r] + 1e-8f);
        e = __expf(lg);
      }
      unsigned short eb = f2bf(e);
      E_t[n * 72 + w * 16 + q * 4 + r] = eb;       // E^T: [col][token]
      lsum += bf2f(eb);                            // denom consistent with bf16 e
    }
    lsum += __shfl_xor(lsum, 16, 64);
    lsum += __shfl_xor(lsum, 32, 64);
    if (lane < 16) atomicAdd(&l_lds[lane], lsum);
    #pragma unroll
    for (int k = 0; k < 8; ++k)
      *(short8*)(tok_lds + (w * 16 + n) * 264 + q * 8 + k * 32) = cur[k];
    __syncthreads();
    short8 ea0 = *(const short8*)(E_t + n * 72 + q * 8);
    short8 ea1 = *(const short8*)(E_t + n * 72 + 32 + q * 8);
    #pragma unroll
    for (int nt = 0; nt < 4; ++nt) {
      const int dcol = w * 64 + nt * 16 + n;
      short8 b0, b1;
      #pragma unroll
      for (int j = 0; j < 8; ++j) b0[j] = (short)tok_lds[(q * 8 + j) * 264 + dcol];
      #pragma unroll
      for (int j = 0; j < 8; ++j) b1[j] = (short)tok_lds[(32 + q * 8 + j) * 264 + dcol];
      sacc[nt] = __builtin_amdgcn_mfma_f32_16x16x32_bf16(ea0, b0, sacc[nt], 0, 0, 0);
      sacc[nt] = __builtin_amdgcn_mfma_f32_16x16x32_bf16(ea1, b1, sacc[nt], 0, 0, 0);
    }
    __syncthreads();
  }

  // epilogue: stage sacc through LDS (tok_lds free), coalesced float4 slab write
  float* stage = (float*)tok_lds;
  #pragma unroll
  for (int nt = 0; nt < 4; ++nt)
    #pragma unroll
    for (int r = 0; r < 4; ++r)
      stage[(q * 4 + r) * 256 + w * 64 + nt * 16 + n] = sacc[nt][r];
  __syncthreads();
  float* sl = slabs + ((size_t)b * S + s) * 4224;
  #pragma unroll
  for (int i = 0; i < 4; ++i) {
    const int row = i * 4 + w;
    const int c0 = (tid & 63) * 4;
    *(floatx4*)(sl + row * 256 + c0) = *(const floatx4*)(stage + row * 256 + c0);
  }
  if (tid < 16) sl[4096 + tid] = l_lds[tid];
}

// ============ staged finalize: batched 4x16 output tiles, K-split waves ============
__global__ __launch_bounds__(256) void k_slab_gemm(
    const float* __restrict__ slabs, int S,
    const float* __restrict__ Wv_p, const float* __restrict__ Wv_c,
    float* __restrict__ X)
{
  __shared__ float act_l[4 * 256];
  __shared__ float lsum[4];
  const int tid = threadIdx.x;
  const int bt = blockIdx.x, nt = blockIdx.y, z = blockIdx.z;
  const int head = nt >> 1;
  const int row = z * 8 + head;
  if (tid < 4) {
    const float* sl = slabs + (size_t)(bt * 4 + tid) * S * 4224;
    float l = 0.f;
    for (int s = 0; s < S; ++s) l += sl[s * 4224 + 4096 + row];
    lsum[tid] = 1.0f / (l + 1e-9f);
  }
  __syncthreads();
  for (int i = tid; i < 4 * 256; i += 256) {
    int m = i >> 8, k = i & 255;
    const float* sl = slabs + (size_t)(bt * 4 + m) * S * 4224;
    float sum = 0.f;
    for (int s = 0; s < S; ++s) sum += sl[s * 4224 + row * 256 + k];
    act_l[i] = sum * lsum[m];
  }
  __syncthreads();
  const int m = tid >> 6, lane = tid & 63, ks = lane >> 4, n = lane & 15;
  const int n0 = nt * 16;
  const float* W = z ? Wv_c : Wv_p;
  float acc = 0.f;
  const float* Wp = W + (size_t)(ks * 64) * 256 + n0 + n;
  const float* ap = &act_l[m * 256 + ks * 64];
  #pragma unroll 8
  for (int k = 0; k < 64; ++k) acc += ap[k] * Wp[(size_t)k * 256];
  acc += __shfl_xor(acc, 16, 64);
  acc += __shfl_xor(acc, 32, 64);
  if (ks == 0)
    X[(size_t)(bt * 4 + m) * 512 + z * 256 + n0 + n] = acc;
}

__global__ __launch_bounds__(256) void k_plain_gemm(
    const float* __restrict__ act, int act_ld,
    const float* __restrict__ W0, const float* __restrict__ W1,
    const float* __restrict__ bias0, const float* __restrict__ bias1,
    float* __restrict__ outp, int out_ld,
    int K, int relu)
{
  __shared__ float act_l[4 * 768];
  const int tid = threadIdx.x;
  const int bt = blockIdx.x, nt = blockIdx.y, z = blockIdx.z;
  const float* W = z ? W1 : W0;
  const float* bias = z ? bias1 : bias0;
  for (int i = tid; i < 4 * K; i += 256) {
    int m = i / K, k = i - m * K;
    act_l[m * K + k] = act[(size_t)(bt * 4 + m) * act_ld + z * K + k];
  }
  __syncthreads();
  const int m = tid >> 6, lane = tid & 63, ks = lane >> 4, n = lane & 15;
  const int n0 = nt * 16;
  const int Kq = K >> 2;
  float acc = 0.f;
  const float* Wp = W + (size_t)(ks * Kq) * 256 + n0 + n;
  const float* ap = &act_l[m * K + ks * Kq];
  #pragma unroll 8
  for (int k = 0; k < Kq; ++k) acc += ap[k] * Wp[(size_t)k * 256];
  acc += __shfl_xor(acc, 16, 64);
  acc += __shfl_xor(acc, 32, 64);
  if (ks == 0) {
    float v = acc + (bias ? bias[n0 + n] : 0.f);
    if (relu) v = fmaxf(v, 0.f);
    outp[(size_t)(bt * 4 + m) * out_ld + z * 256 + n0 + n] = v;
  }
}

__global__ __launch_bounds__(256) void k_ln_gemm(
    const float* __restrict__ node, const int* __restrict__ tgt_idx,
    const float* __restrict__ zbuf,
    const float* __restrict__ ln_g, const float* __restrict__ ln_b,
    const float* __restrict__ fuse_W1, const float* __restrict__ fuse_b1,
    float* __restrict__ h1)
{
  __shared__ float act_l[4 * 768];
  const int tid = threadIdx.x;
  const int bt = blockIdx.x, nt = blockIdx.y;
  for (int i = tid; i < 4 * 256; i += 256) {
    int m = i >> 8, k = i & 255;
    int b = bt * 4 + m;
    float tg = node[(size_t)tgt_idx[b] * 256 + k];
    float C  = zbuf[(size_t)b * 512 + k];
    float Fp = zbuf[(size_t)b * 512 + 256 + k];
    act_l[m * 768 + k]       = tg;
    act_l[m * 768 + 256 + k] = C;
    act_l[m * 768 + 512 + k] = tg + Fp;
  }
  __syncthreads();
  const int m = tid >> 6, lane = tid & 63;
  {
    float s = 0.f;
    for (int k = lane; k < 768; k += 64) s += act_l[m * 768 + k];
    #pragma unroll
    for (int o = 32; o >= 1; o >>= 1) s += __shfl_xor(s, o, 64);
    const float mu = s * (1.0f / 768.0f);
    float v = 0.f;
    for (int k = lane; k < 768; k += 64) { float d = act_l[m * 768 + k] - mu; v += d * d; }
    #pragma unroll
    for (int o = 32; o >= 1; o >>= 1) v += __shfl_xor(v, o, 64);
    const float rstd = 1.0f / sqrtf(v * (1.0f / 768.0f) + 1e-5f);
    for (int k = lane; k < 768; k += 64)
      act_l[m * 768 + k] = (act_l[m * 768 + k] - mu) * rstd * ln_g[k] + ln_b[k];
  }
  __syncthreads();
  const int ks = lane >> 4, n = lane & 15;
  const int n0 = nt * 16;
  float acc = 0.f;
  const float* Wp = fuse_W1 + (size_t)(ks * 192) * 256 + n0 + n;
  const float* ap = &act_l[m * 768 + ks * 192];
  #pragma unroll 8
  for (int k = 0; k < 192; ++k) acc += ap[k] * Wp[(size_t)k * 256];
  acc += __shfl_xor(acc, 16, 64);
  acc += __shfl_xor(acc, 32, 64);
  if (ks == 0)
    h1[(size_t)(bt * 4 + m) * 256 + n0 + n] = fmaxf(acc + fuse_b1[n0 + n], 0.f);
}

__global__ __launch_bounds__(256) void k_outhead(
    const float* __restrict__ hh, const float* __restrict__ head_W2,
    const float* __restrict__ head_b2, float* __restrict__ out)
{
  const int tid = threadIdx.x;
  const int m = tid >> 6, lane = tid & 63;
  const int b = blockIdx.x * 4 + m;
  float a0 = 0.f, a1 = 0.f, a2 = 0.f;
  for (int k = lane; k < 256; k += 64) {
    float h = hh[(size_t)b * 256 + k];
    a0 += h * head_W2[k * 3 + 0];
    a1 += h * head_W2[k * 3 + 1];
    a2 += h * head_W2[k * 3 + 2];
  }
  #pragma unroll
  for (int o = 32; o >= 1; o >>= 1) {
    a0 += __shfl_xor(a0, o, 64);
    a1 += __shfl_xor(a1, o, 64);
    a2 += __shfl_xor(a2, o, 64);
  }
  if (lane == 0) {
    out[b * 3 + 0] = a0 + head_b2[0];
    out[b * 3 + 1] = a1 + head_b2[1];
    out[b * 3 + 2] = a2 + head_b2[2];
  }
}

extern "C" void kernel_launch(void* const* d_in, const int* in_sizes, int n_in,
                              void* d_out, int out_size, void* d_ws, size_t ws_size,
                              hipStream_t stream) {
  const float* node        = (const float*)d_in[0];
  const int*   tgt_idx     = (const int*)d_in[1];
  const int*   port_index  = (const int*)d_in[2];
  const int*   port_batch  = (const int*)d_in[3];
  const float* port_weight = (const float*)d_in[4];
  const float* seed        = (const float*)d_in[5];
  const float* Wq_p = (const float*)d_in[6];
  const float* Wk_p = (const float*)d_in[7];
  const float* Wv_p = (const float*)d_in[8];
  const float* Wo_p = (const float*)d_in[9];
  const float* Wq_c = (const float*)d_in[10];
  const float* Wk_c = (const float*)d_in[11];
  const float* Wv_c = (const float*)d_in[12];
  const float* Wo_c = (const float*)d_in[13];
  const float* ln_g = (const float*)d_in[14];
  const float* ln_b = (const float*)d_in[15];
  const float* fuse_W1 = (const float*)d_in[16];
  const float* fuse_b1 = (const float*)d_in[17];
  const float* fuse_W2 = (const float*)d_in[18];
  const float* fuse_b2 = (const float*)d_in[19];
  const float* head_W1 = (const float*)d_in[20];
  const float* head_b1 = (const float*)d_in[21];
  const float* head_W2 = (const float*)d_in[22];
  const float* head_b2 = (const float*)d_in[23];

  const int B = in_sizes[1];
  const int T = in_sizes[2];

  // ws layout:
  //   0           u_p_t (4 KB)
  //   4096        seg   ((B+1)*4, padded)
  //   8192        u_c_all (B*2048*2 = 1 MB)  [setup->attn]  -- overlaid later by:
  //   8192        X    (B*512*4)   [stage L1 out]
  //   8192+512K   zbuf (B*512*4)   [stage L2 out]
  //   8192+1M     slabs (B*S*4224*4, S<=8)   -- overlaid later by h1/z2/hh
  //   8192+1M+8*per_slice   q_all ((B+1)*256*4)
  char* ws = (char*)d_ws;
  unsigned short* u_p_t   = (unsigned short*)ws;
  int*            seg     = (int*)(ws + 4096);
  unsigned short* u_c_all = (unsigned short*)(ws + 8192);
  float* X    = (float*)(ws + 8192);
  float* zbuf = (float*)(ws + 8192 + (size_t)B * 2048);
  size_t slab_off = 8192 + (size_t)B * 4096;
  float* slabs = (float*)(ws + slab_off);
  float* h1 = slabs;
  float* z2 = h1 + (size_t)B * 256;
  float* hh = z2 + (size_t)B * 256;

  size_t per_slice = (size_t)B * 4224 * 4;
  size_t q_off = slab_off + 8 * per_slice;
  float* q_all = (float*)(ws + q_off);

  int S = 1;
  if (ws_size > slab_off + per_slice) {
    size_t fit = (ws_size - slab_off - ((size_t)(B + 1) * 1024 + 4096)) / per_slice;
    S = (int)(fit < 1 ? 1 : (fit > 8 ? 8 : fit));
  }
  if (S < 8) q_all = (float*)(ws + slab_off + (size_t)S * per_slice);  // shrink if ws small

  const int BT = B / 4;   // 64 b-tiles

  k_qc_gemm<<<dim3(BT + 1, 16), 256, 0, stream>>>(node, tgt_idx, seed,
      Wq_c, Wq_p, q_all, B);
  k_fold<<<dim3(BT + 1, 16), 256, 0, stream>>>(Wk_c, Wk_p, q_all, port_batch,
      u_c_all, u_p_t, seg, T, B);
  attn_kernel<<<dim3(S, B), 256, 0, stream>>>(node, port_index, port_weight,
      u_p_t, u_c_all, seg, slabs, T, S);
  k_slab_gemm<<<dim3(BT, 16, 2), 256, 0, stream>>>(slabs, S, Wv_p, Wv_c, X);
  k_plain_gemm<<<dim3(BT, 16, 2), 256, 0, stream>>>(X, 512, Wo_p, Wo_c,
      nullptr, nullptr, zbuf, 512, 256, 0);
  k_ln_gemm<<<dim3(BT, 16), 256, 0, stream>>>(node, tgt_idx, zbuf,
      ln_g, ln_b, fuse_W1, fuse_b1, h1);
  k_plain_gemm<<<dim3(BT, 16, 1), 256, 0, stream>>>(h1, 256, fuse_W2, nullptr,
      fuse_b2, nullptr, z2, 256, 256, 0);
  k_plain_gemm<<<dim3(BT, 16, 1), 256, 0, stream>>>(z2, 256, head_W1, nullptr,
      head_b1, nullptr, hh, 256, 256, 1);
  k_outhead<<<BT, 256, 0, stream>>>(hh, head_W2, head_b2, (float*)d_out);
}

// Round 7
// 303.219 us; speedup vs baseline: 1.0576x; 1.0576x over previous
//
#include <hip/hip_runtime.h>
#include <hip/hip_bf16.h>

typedef __attribute__((ext_vector_type(8))) short short8;
typedef __attribute__((ext_vector_type(4))) float floatx4;

#define SCALE 0.17677669529663687f  /* 1/sqrt(32) */

__device__ __forceinline__ unsigned short f2bf(float f) {
  unsigned int x = __float_as_uint(f);
  x += 0x7fffu + ((x >> 16) & 1u);   // RNE
  return (unsigned short)(x >> 16);
}
__device__ __forceinline__ float bf2f(unsigned short u) {
  return __uint_as_float(((unsigned int)u) << 16);
}

// ---------------- setup A: q_all[b,:] = tgt_b @ Wq_c  (row B = seed @ Wq_p) ----------------
__global__ __launch_bounds__(256) void k_qc_gemm(
    const float* __restrict__ node, const int* __restrict__ tgt_idx,
    const float* __restrict__ seed,
    const float* __restrict__ Wq_c, const float* __restrict__ Wq_p,
    float* __restrict__ q_all, int B)
{
  __shared__ float act_l[4 * 256];
  const int tid = threadIdx.x;
  const int bt = blockIdx.x, nt = blockIdx.y;
  const int BT = B >> 2;
  for (int i = tid; i < 4 * 256; i += 256) {
    int m = i >> 8, k = i & 255;
    int b = bt * 4 + m;
    float v = 0.f;
    if (b < B)       v = node[(size_t)tgt_idx[b] * 256 + k];
    else if (b == B) v = seed[k];
    act_l[i] = v;
  }
  __syncthreads();
  const float* W = (bt == BT) ? Wq_p : Wq_c;
  const int m = tid >> 6, lane = tid & 63, ks = lane >> 4, n = lane & 15;
  const int n0 = nt * 16;
  float acc = 0.f;
  const float* Wp = W + (size_t)(ks * 64) * 256 + n0 + n;
  const float* ap = &act_l[m * 256 + ks * 64];
  #pragma unroll 8
  for (int k = 0; k < 64; ++k) acc += ap[k] * Wp[(size_t)k * 256];
  acc += __shfl_xor(acc, 16, 64);
  acc += __shfl_xor(acc, 32, 64);
  const int b = bt * 4 + m;
  if (ks == 0 && b <= B) q_all[(size_t)b * 256 + n0 + n] = acc;
}

// ---------------- setup B: per-head fold u[b][h][d] = sum_j Wk[d, h*32+j] q[b, h*32+j] ----------------
__global__ __launch_bounds__(256) void k_fold(
    const float* __restrict__ Wk_c, const float* __restrict__ Wk_p,
    const float* __restrict__ q_all, const int* __restrict__ port_batch,
    unsigned short* __restrict__ u_c_all, unsigned short* __restrict__ u_p_t,
    int* __restrict__ seg, int T, int B)
{
  const int tid = threadIdx.x;
  const int bt = blockIdx.x, dt = blockIdx.y;
  const int BT = B >> 2;
  if (dt == 0) {
    int key = -1;
    if (bt < BT) { if (tid < 4) key = bt * 4 + tid; }
    else if (tid == 0) key = B;
    if (key >= 0) {
      int lo = 0, hi = T;
      while (lo < hi) { int mid = (lo + hi) >> 1; if (port_batch[mid] < key) lo = mid + 1; else hi = mid; }
      seg[key] = lo;
    }
  }
  const int m = tid >> 6, lane = tid & 63;
  const int b = bt * 4 + m;
  if (b > B) return;
  const float* Wk = (b == B) ? Wk_p : Wk_c;
  const float* q = q_all + (size_t)b * 256;
  #pragma unroll
  for (int t2 = 0; t2 < 2; ++t2) {
    const int idx = t2 * 64 + lane;
    const int h = idx >> 4;
    const int d = dt * 16 + (idx & 15);
    float acc = 0.f;
    const float* wr = Wk + (size_t)d * 256 + h * 32;
    const float* qr = q + h * 32;
    #pragma unroll 8
    for (int j = 0; j < 32; ++j) acc += wr[j] * qr[j];
    unsigned short v = f2bf(acc);
    if (b < B) u_c_all[(size_t)b * 2048 + h * 256 + d] = v;
    else       u_p_t[h * 256 + d] = v;
  }
}

// ---------------- attention: WG (s, b) handles tiles s, s+S, ... of segment b ----------------
// Dense gather: each vmem instruction loads ONE full 1KB row (64 lanes x 16B contiguous),
// converts to bf16, stages into LDS; MFMA A-frags read back via contiguous ds_read_b128.
__global__ __launch_bounds__(256, 2) void attn_kernel(
    const float* __restrict__ node,
    const int* __restrict__ port_index,
    const float* __restrict__ port_weight,
    const unsigned short* __restrict__ u_p_t,
    const unsigned short* __restrict__ u_c_all,
    const int* __restrict__ seg,
    float* __restrict__ slabs, int T, int S)
{
  __shared__ __align__(16) unsigned short tok_lds[64 * 264];
  __shared__ __align__(16) unsigned short E_t[16 * 72];
  __shared__ float l_lds[16];

  const int tid  = threadIdx.x;
  const int s    = blockIdx.x;
  const int b    = blockIdx.y;
  const int lane = tid & 63;
  const int w    = tid >> 6;
  const int q    = lane >> 4;
  const int n    = lane & 15;

  if (tid < 16) l_lds[tid] = 0.f;

  short8 ufrag[8];
  const unsigned short* ubase = (n < 8) ? (u_p_t + n * 256)
                                        : (u_c_all + (size_t)b * 2048 + (n - 8) * 256);
  #pragma unroll
  for (int s8 = 0; s8 < 8; ++s8)
    ufrag[s8] = *(const short8*)(ubase + q * 8 + s8 * 32);

  const int start  = seg[b];
  const int end    = seg[b + 1];
  const int ntiles = (end - start + 63) >> 6;

  floatx4 sacc[4];
  #pragma unroll
  for (int nt = 0; nt < 4; ++nt) sacc[nt] = (floatx4){0.f, 0.f, 0.f, 0.f};

  __syncthreads();   // l_lds init visible

  for (int it = s; it < ntiles; it += S) {
    const int tbase = start + it * 64;
    // dense gather: wave w stages its 16 token rows (1KB each, fully contiguous)
    {
      int t0 = tbase + w * 16 + n;
      int idxv = port_index[t0 < T ? t0 : T - 1];
      #pragma unroll
      for (int i = 0; i < 16; ++i) {
        int rb = __shfl(idxv, i, 64);
        floatx4 v = *(const floatx4*)(node + (size_t)rb * 256 + lane * 4);
        unsigned int p0 = (unsigned int)f2bf(v[0]) | ((unsigned int)f2bf(v[1]) << 16);
        unsigned int p1 = (unsigned int)f2bf(v[2]) | ((unsigned int)f2bf(v[3]) << 16);
        uint2 pk; pk.x = p0; pk.y = p1;
        *(uint2*)(tok_lds + (w * 16 + i) * 264 + lane * 4) = pk;
      }
    }
    float pw[4];
    #pragma unroll
    for (int r = 0; r < 4; ++r) { int tr = tbase + w * 16 + q * 4 + r; pw[r] = port_weight[tr < T ? tr : T - 1]; }

    // phase 1: logits = tok_tile[16x256] @ U[256x16]; A-frags from LDS (own wave's rows)
    floatx4 lacc = (floatx4){0.f, 0.f, 0.f, 0.f};
    #pragma unroll
    for (int k = 0; k < 8; ++k) {
      short8 af = *(const short8*)(tok_lds + (w * 16 + n) * 264 + q * 8 + k * 32);
      lacc = __builtin_amdgcn_mfma_f32_16x16x32_bf16(af, ufrag[k], lacc, 0, 0, 0);
    }
    float lsum = 0.f;
    #pragma unroll
    for (int r = 0; r < 4; ++r) {
      const int tr = tbase + w * 16 + q * 4 + r;
      float e = 0.f;
      if (tr < end) {
        float lg = lacc[r] * SCALE + logf(pw[r] + 1e-8f);
        e = __expf(lg);
      }
      unsigned short eb = f2bf(e);
      E_t[n * 72 + w * 16 + q * 4 + r] = eb;       // E^T: [col][token]
      lsum += bf2f(eb);                            // denom consistent with bf16 e
    }
    lsum += __shfl_xor(lsum, 16, 64);
    lsum += __shfl_xor(lsum, 32, 64);
    if (lane < 16) atomicAdd(&l_lds[lane], lsum);
    __syncthreads();
    // phase 2: sums[16 cols][256 d] += E^T[16x64] @ tok[64x256]; wave w owns d slice
    short8 ea0 = *(const short8*)(E_t + n * 72 + q * 8);
    short8 ea1 = *(const short8*)(E_t + n * 72 + 32 + q * 8);
    #pragma unroll
    for (int nt = 0; nt < 4; ++nt) {
      const int dcol = w * 64 + nt * 16 + n;
      short8 b0, b1;
      #pragma unroll
      for (int j = 0; j < 8; ++j) b0[j] = (short)tok_lds[(q * 8 + j) * 264 + dcol];
      #pragma unroll
      for (int j = 0; j < 8; ++j) b1[j] = (short)tok_lds[(32 + q * 8 + j) * 264 + dcol];
      sacc[nt] = __builtin_amdgcn_mfma_f32_16x16x32_bf16(ea0, b0, sacc[nt], 0, 0, 0);
      sacc[nt] = __builtin_amdgcn_mfma_f32_16x16x32_bf16(ea1, b1, sacc[nt], 0, 0, 0);
    }
    __syncthreads();
  }

  // epilogue: stage sacc through LDS (tok_lds free), coalesced float4 slab write
  float* stage = (float*)tok_lds;
  #pragma unroll
  for (int nt = 0; nt < 4; ++nt)
    #pragma unroll
    for (int r = 0; r < 4; ++r)
      stage[(q * 4 + r) * 256 + w * 64 + nt * 16 + n] = sacc[nt][r];
  __syncthreads();
  float* sl = slabs + ((size_t)b * S + s) * 4224;
  #pragma unroll
  for (int i = 0; i < 4; ++i) {
    const int row = i * 4 + w;
    const int c0 = (tid & 63) * 4;
    *(floatx4*)(sl + row * 256 + c0) = *(const floatx4*)(stage + row * 256 + c0);
  }
  if (tid < 16) sl[4096 + tid] = l_lds[tid];
}

// ============ staged finalize: batched 4x16 output tiles, K-split waves ============
__global__ __launch_bounds__(256) void k_slab_gemm(
    const float* __restrict__ slabs, int S,
    const float* __restrict__ Wv_p, const float* __restrict__ Wv_c,
    float* __restrict__ X)
{
  __shared__ float act_l[4 * 256];
  __shared__ float lsum[4];
  const int tid = threadIdx.x;
  const int bt = blockIdx.x, nt = blockIdx.y, z = blockIdx.z;
  const int head = nt >> 1;
  const int row = z * 8 + head;
  if (tid < 4) {
    const float* sl = slabs + (size_t)(bt * 4 + tid) * S * 4224;
    float l = 0.f;
    for (int s = 0; s < S; ++s) l += sl[s * 4224 + 4096 + row];
    lsum[tid] = 1.0f / (l + 1e-9f);
  }
  __syncthreads();
  for (int i = tid; i < 4 * 256; i += 256) {
    int m = i >> 8, k = i & 255;
    const float* sl = slabs + (size_t)(bt * 4 + m) * S * 4224;
    float sum = 0.f;
    for (int s = 0; s < S; ++s) sum += sl[s * 4224 + row * 256 + k];
    act_l[i] = sum * lsum[m];
  }
  __syncthreads();
  const int m = tid >> 6, lane = tid & 63, ks = lane >> 4, n = lane & 15;
  const int n0 = nt * 16;
  const float* W = z ? Wv_c : Wv_p;
  float acc = 0.f;
  const float* Wp = W + (size_t)(ks * 64) * 256 + n0 + n;
  const float* ap = &act_l[m * 256 + ks * 64];
  #pragma unroll 8
  for (int k = 0; k < 64; ++k) acc += ap[k] * Wp[(size_t)k * 256];
  acc += __shfl_xor(acc, 16, 64);
  acc += __shfl_xor(acc, 32, 64);
  if (ks == 0)
    X[(size_t)(bt * 4 + m) * 512 + z * 256 + n0 + n] = acc;
}

__global__ __launch_bounds__(256) void k_plain_gemm(
    const float* __restrict__ act, int act_ld,
    const float* __restrict__ W0, const float* __restrict__ W1,
    const float* __restrict__ bias0, const float* __restrict__ bias1,
    float* __restrict__ outp, int out_ld,
    int K, int relu)
{
  __shared__ float act_l[4 * 768];
  const int tid = threadIdx.x;
  const int bt = blockIdx.x, nt = blockIdx.y, z = blockIdx.z;
  const float* W = z ? W1 : W0;
  const float* bias = z ? bias1 : bias0;
  for (int i = tid; i < 4 * K; i += 256) {
    int m = i / K, k = i - m * K;
    act_l[m * K + k] = act[(size_t)(bt * 4 + m) * act_ld + z * K + k];
  }
  __syncthreads();
  const int m = tid >> 6, lane = tid & 63, ks = lane >> 4, n = lane & 15;
  const int n0 = nt * 16;
  const int Kq = K >> 2;
  float acc = 0.f;
  const float* Wp = W + (size_t)(ks * Kq) * 256 + n0 + n;
  const float* ap = &act_l[m * K + ks * Kq];
  #pragma unroll 8
  for (int k = 0; k < Kq; ++k) acc += ap[k] * Wp[(size_t)k * 256];
  acc += __shfl_xor(acc, 16, 64);
  acc += __shfl_xor(acc, 32, 64);
  if (ks == 0) {
    float v = acc + (bias ? bias[n0 + n] : 0.f);
    if (relu) v = fmaxf(v, 0.f);
    outp[(size_t)(bt * 4 + m) * out_ld + z * 256 + n0 + n] = v;
  }
}

__global__ __launch_bounds__(256) void k_ln_gemm(
    const float* __restrict__ node, const int* __restrict__ tgt_idx,
    const float* __restrict__ zbuf,
    const float* __restrict__ ln_g, const float* __restrict__ ln_b,
    const float* __restrict__ fuse_W1, const float* __restrict__ fuse_b1,
    float* __restrict__ h1)
{
  __shared__ float act_l[4 * 768];
  const int tid = threadIdx.x;
  const int bt = blockIdx.x, nt = blockIdx.y;
  for (int i = tid; i < 4 * 256; i += 256) {
    int m = i >> 8, k = i & 255;
    int b = bt * 4 + m;
    float tg = node[(size_t)tgt_idx[b] * 256 + k];
    float C  = zbuf[(size_t)b * 512 + k];
    float Fp = zbuf[(size_t)b * 512 + 256 + k];
    act_l[m * 768 + k]       = tg;
    act_l[m * 768 + 256 + k] = C;
    act_l[m * 768 + 512 + k] = tg + Fp;
  }
  __syncthreads();
  const int m = tid >> 6, lane = tid & 63;
  {
    float s = 0.f;
    for (int k = lane; k < 768; k += 64) s += act_l[m * 768 + k];
    #pragma unroll
    for (int o = 32; o >= 1; o >>= 1) s += __shfl_xor(s, o, 64);
    const float mu = s * (1.0f / 768.0f);
    float v = 0.f;
    for (int k = lane; k < 768; k += 64) { float d = act_l[m * 768 + k] - mu; v += d * d; }
    #pragma unroll
    for (int o = 32; o >= 1; o >>= 1) v += __shfl_xor(v, o, 64);
    const float rstd = 1.0f / sqrtf(v * (1.0f / 768.0f) + 1e-5f);
    for (int k = lane; k < 768; k += 64)
      act_l[m * 768 + k] = (act_l[m * 768 + k] - mu) * rstd * ln_g[k] + ln_b[k];
  }
  __syncthreads();
  const int ks = lane >> 4, n = lane & 15;
  const int n0 = nt * 16;
  float acc = 0.f;
  const float* Wp = fuse_W1 + (size_t)(ks * 192) * 256 + n0 + n;
  const float* ap = &act_l[m * 768 + ks * 192];
  #pragma unroll 8
  for (int k = 0; k < 192; ++k) acc += ap[k] * Wp[(size_t)k * 256];
  acc += __shfl_xor(acc, 16, 64);
  acc += __shfl_xor(acc, 32, 64);
  if (ks == 0)
    h1[(size_t)(bt * 4 + m) * 256 + n0 + n] = fmaxf(acc + fuse_b1[n0 + n], 0.f);
}

__global__ __launch_bounds__(256) void k_outhead(
    const float* __restrict__ hh, const float* __restrict__ head_W2,
    const float* __restrict__ head_b2, float* __restrict__ out)
{
  const int tid = threadIdx.x;
  const int m = tid >> 6, lane = tid & 63;
  const int b = blockIdx.x * 4 + m;
  float a0 = 0.f, a1 = 0.f, a2 = 0.f;
  for (int k = lane; k < 256; k += 64) {
    float h = hh[(size_t)b * 256 + k];
    a0 += h * head_W2[k * 3 + 0];
    a1 += h * head_W2[k * 3 + 1];
    a2 += h * head_W2[k * 3 + 2];
  }
  #pragma unroll
  for (int o = 32; o >= 1; o >>= 1) {
    a0 += __shfl_xor(a0, o, 64);
    a1 += __shfl_xor(a1, o, 64);
    a2 += __shfl_xor(a2, o, 64);
  }
  if (lane == 0) {
    out[b * 3 + 0] = a0 + head_b2[0];
    out[b * 3 + 1] = a1 + head_b2[1];
    out[b * 3 + 2] = a2 + head_b2[2];
  }
}

extern "C" void kernel_launch(void* const* d_in, const int* in_sizes, int n_in,
                              void* d_out, int out_size, void* d_ws, size_t ws_size,
                              hipStream_t stream) {
  const float* node        = (const float*)d_in[0];
  const int*   tgt_idx     = (const int*)d_in[1];
  const int*   port_index  = (const int*)d_in[2];
  const int*   port_batch  = (const int*)d_in[3];
  const float* port_weight = (const float*)d_in[4];
  const float* seed        = (const float*)d_in[5];
  const float* Wq_p = (const float*)d_in[6];
  const float* Wk_p = (const float*)d_in[7];
  const float* Wv_p = (const float*)d_in[8];
  const float* Wo_p = (const float*)d_in[9];
  const float* Wq_c = (const float*)d_in[10];
  const float* Wk_c = (const float*)d_in[11];
  const float* Wv_c = (const float*)d_in[12];
  const float* Wo_c = (const float*)d_in[13];
  const float* ln_g = (const float*)d_in[14];
  const float* ln_b = (const float*)d_in[15];
  const float* fuse_W1 = (const float*)d_in[16];
  const float* fuse_b1 = (const float*)d_in[17];
  const float* fuse_W2 = (const float*)d_in[18];
  const float* fuse_b2 = (const float*)d_in[19];
  const float* head_W1 = (const float*)d_in[20];
  const float* head_b1 = (const float*)d_in[21];
  const float* head_W2 = (const float*)d_in[22];
  const float* head_b2 = (const float*)d_in[23];

  const int B = in_sizes[1];
  const int T = in_sizes[2];

  char* ws = (char*)d_ws;
  unsigned short* u_p_t   = (unsigned short*)ws;
  int*            seg     = (int*)(ws + 4096);
  unsigned short* u_c_all = (unsigned short*)(ws + 8192);
  float* X    = (float*)(ws + 8192);
  float* zbuf = (float*)(ws + 8192 + (size_t)B * 2048);
  size_t slab_off = 8192 + (size_t)B * 4096;
  float* slabs = (float*)(ws + slab_off);
  float* h1 = slabs;
  float* z2 = h1 + (size_t)B * 256;
  float* hh = z2 + (size_t)B * 256;

  size_t per_slice = (size_t)B * 4224 * 4;
  int S = 1;
  if (ws_size > slab_off + per_slice) {
    size_t fit = (ws_size - slab_off - ((size_t)(B + 1) * 1024 + 4096)) / per_slice;
    S = (int)(fit < 1 ? 1 : (fit > 4 ? 4 : fit));   // S=4: 4 WGs/CU, ~2 tiles/WG
  }
  float* q_all = (float*)(ws + slab_off + (size_t)S * per_slice);

  const int BT = B / 4;   // 64 b-tiles

  k_qc_gemm<<<dim3(BT + 1, 16), 256, 0, stream>>>(node, tgt_idx, seed,
      Wq_c, Wq_p, q_all, B);
  k_fold<<<dim3(BT + 1, 16), 256, 0, stream>>>(Wk_c, Wk_p, q_all, port_batch,
      u_c_all, u_p_t, seg, T, B);
  attn_kernel<<<dim3(S, B), 256, 0, stream>>>(node, port_index, port_weight,
      u_p_t, u_c_all, seg, slabs, T, S);
  k_slab_gemm<<<dim3(BT, 16, 2), 256, 0, stream>>>(slabs, S, Wv_p, Wv_c, X);
  k_plain_gemm<<<dim3(BT, 16, 2), 256, 0, stream>>>(X, 512, Wo_p, Wo_c,
      nullptr, nullptr, zbuf, 512, 256, 0);
  k_ln_gemm<<<dim3(BT, 16), 256, 0, stream>>>(node, tgt_idx, zbuf,
      ln_g, ln_b, fuse_W1, fuse_b1, h1);
  k_plain_gemm<<<dim3(BT, 16, 1), 256, 0, stream>>>(h1, 256, fuse_W2, nullptr,
      fuse_b2, nullptr, z2, 256, 256, 0);
  k_plain_gemm<<<dim3(BT, 16, 1), 256, 0, stream>>>(z2, 256, head_W1, nullptr,
      head_b1, nullptr, hh, 256, 256, 1);
  k_outhead<<<BT, 256, 0, stream>>>(hh, head_W2, head_b2, (float*)d_out);
}